// Round 7
// baseline (1698.990 us; speedup 1.0000x reference)
//
#include <hip/hip_runtime.h>

#define BB 256
#define TT 512
#define HH 512
#define NTH 512
#define XELEMS (BB * HH)   // f32x2 elements per exchange ping-pong slot

typedef float f32x4 __attribute__((ext_vector_type(4)));
typedef float f32x2 __attribute__((ext_vector_type(2)));

// packed fp32 FMA: d = a*b + c on both lanes -> v_pk_fma_f32 (full-rate on CDNA3+)
__device__ __forceinline__ f32x2 pk_fma(f32x2 a, f32x2 b, f32x2 c) {
    return __builtin_elementwise_fma(a, b, c);
}

// cross-lane move via DPP (VALU pipe)
template<int CTRL>
__device__ __forceinline__ float dpp_mov(float v) {
    return __builtin_bit_cast(float, __builtin_amdgcn_update_dpp(
        0, __builtin_bit_cast(int, v), CTRL, 0xf, 0xf, true));
}
// lane ^= 4 via ds_swizzle (xor_mask=4, and_mask=0x1F)
__device__ __forceinline__ float swz_xor4(float v) {
    return __builtin_bit_cast(float, __builtin_amdgcn_ds_swizzle(
        __builtin_bit_cast(int, v), 0x101F));
}

// Pair-split RNN (R7): packed-fp32 FMA + batch-innermost weight sweep.
// WG bid owns j-half jh=bid&1 (256x512 = 512 KB: 192 fl/thread regs (incl.
// AGPR overflow, 1 copy/weight/step) + 64 fl/thread LDS). Tagged ping-pong
// exchange via d_ws sc0sc1 (L3-coherent), unchanged from R6.
__global__ void
__attribute__((amdgpu_flat_work_group_size(NTH, NTH)))
__attribute__((amdgpu_waves_per_eu(2, 2)))
rnn_pair_kernel(
    const float* __restrict__ x,    // [B, T, 2]
    const float* __restrict__ Wh,   // [H, H]
    const float* __restrict__ Wx,   // [H, 2]
    float* __restrict__ out,        // [T+1, B, H]
    f32x2* __restrict__ xch)        // [2][B][H] (value, tag) exchange
{
    const int bid = blockIdx.x;
    const int tid = threadIdx.x;
    const int jh  = bid & 1;
    const int g   = bid >> 1;
    const int b0  = g * 2;
    const int kt  = tid & 15;              // k-chunk (16 floats per half)
    const int jg  = tid >> 4;              // j-group 0..31 (8 rows each)
    const int wv  = tid >> 6;              // wave id
    const int ln  = tid & 63;              // lane id

    const int J0   = jh * 256;             // owned rows
    const int Jpar = (1 - jh) * 256;       // partner rows
    const int krow_own = J0   + kt * 16;
    const int krow_par = Jpar + kt * 16;

    __shared__ __align__(16) float wlds[32768];      // 128 KB partner-weight tails
    __shared__ __align__(16) float hbuf[2][2][320];  // own-half h, padded 16x20
    __shared__ __align__(16) float pstage[2][320];   // partner-half h, padded
    __shared__ __align__(16) float xs[2][TT * 2];    // x stash

    // ---- x stash ----
    {
        int bsel = tid >> 8, idx = tid & 255;
        f32x4 v = reinterpret_cast<const f32x4*>(x + (size_t)(b0 + bsel) * (TT * 2))[idx];
        reinterpret_cast<f32x4*>(&xs[bsel][0])[idx] = v;
    }

    // ---- weights: own 16k (8 pairs) in regs, partner k0..7 (4 pairs) in regs,
    //      partner k8..15 -> LDS ----
    f32x2 wown2[8][8], wpar2[8][4];
    #pragma unroll
    for (int jj = 0; jj < 8; ++jj) {
        const float* row = Wh + (size_t)(J0 + jg * 8 + jj) * HH;
        const f32x4* o4 = reinterpret_cast<const f32x4*>(row + krow_own);
        #pragma unroll
        for (int q = 0; q < 4; ++q) {
            f32x4 v = o4[q];
            wown2[jj][2*q + 0] = f32x2{v[0], v[1]};
            wown2[jj][2*q + 1] = f32x2{v[2], v[3]};
        }
        const f32x4* p4 = reinterpret_cast<const f32x4*>(row + krow_par);
        #pragma unroll
        for (int q = 0; q < 2; ++q) {
            f32x4 v = p4[q];
            wpar2[jj][2*q + 0] = f32x2{v[0], v[1]};
            wpar2[jj][2*q + 1] = f32x2{v[2], v[3]};
        }
        #pragma unroll
        for (int q = 2; q < 4; ++q) {
            int qq = jj * 2 + (q - 2);
            reinterpret_cast<f32x4*>(wlds)[wv * 1024 + qq * 64 + ln] = p4[q];
        }
    }

    // ---- h0 init ----
    for (int i = tid; i < 2 * 2 * 320; i += NTH) (&hbuf[0][0][0])[i] = 0.f;
    for (int i = tid; i < 2 * 320;     i += NTH) (&pstage[0][0])[i]  = 0.f;
    __syncthreads();
    if (tid == 0) {
        if (jh == 0) { hbuf[0][0][0] = 1.f; hbuf[0][1][0] = 1.f; }
        else         { pstage[0][0]  = 1.f; pstage[1][0]  = 1.f; }
    }
    // out[0]
    if (tid < 128) {
        int b = tid >> 6, c = tid & 63;
        f32x4 z;
        z[0] = (jh == 0 && c == 0) ? 1.f : 0.f; z[1] = 0.f; z[2] = 0.f; z[3] = 0.f;
        *reinterpret_cast<f32x4*>(out + (size_t)(b0 + b) * HH + J0 + c * 4) = z;
    }

    // writer identity: lane kt holds final value v=kt -> (batch kt>>3, col jg*8+(kt&7))
    const int bw = kt >> 3;
    const int jw = J0 + jg * 8 + (kt & 7);
    const float wx0 = Wx[jw * 2 + 0];
    const float wx1 = Wx[jw * 2 + 1];
    const int jl = jw - J0;
    const int wslot = (jl >> 4) * 20 + (jl & 15);

    // exchange addressing
    const int rb = tid >> 8, ri = tid & 255;             // reader: batch-local, h-local
    const f32x2* rdb = xch + (size_t)(b0 + rb) * HH + Jpar + ri;      // + slot*XELEMS
    f32x2*       pub = xch + (size_t)(b0 + bw) * HH + jw;             // + slot*XELEMS
    const int pslot2 = (ri >> 4) * 20 + (ri & 15);       // pstage landing slot
    const size_t ostep = (size_t)BB * HH;

    __syncthreads();
    int cur = 0;

    for (int t = 0; t < TT; ++t) {
        // A. issue partner-half tagged load (t=0: pstage pre-filled analytically)
        f32x2 pv;
        const bool ld = (t > 0);
        const f32x2* pa = rdb + ((t & 1) ? XELEMS : 0);
        if (ld)
            asm volatile("global_load_dwordx2 %0, %1, off sc0 sc1"
                         : "=&v"(pv) : "v"(pa) : "memory");

        // B. phase1: own-half packed FMAs, batch innermost (1 weight read, 2 uses)
        f32x2 acc2[8][2];
        #pragma unroll
        for (int jj = 0; jj < 8; ++jj) {
            acc2[jj][0] = f32x2{0.f, 0.f};
            acc2[jj][1] = f32x2{0.f, 0.f};
        }
        {
            const float* h0p = &hbuf[cur][0][kt * 20];
            const float* h1p = &hbuf[cur][1][kt * 20];
            #pragma unroll
            for (int q = 0; q < 4; ++q) {
                f32x4 a4 = *reinterpret_cast<const f32x4*>(h0p + q * 4);
                f32x4 b4 = *reinterpret_cast<const f32x4*>(h1p + q * 4);
                #pragma unroll
                for (int e2 = 0; e2 < 2; ++e2) {
                    f32x2 ha = f32x2{a4[2*e2], a4[2*e2+1]};
                    f32x2 hb = f32x2{b4[2*e2], b4[2*e2+1]};
                    #pragma unroll
                    for (int jj = 0; jj < 8; ++jj) {
                        f32x2 w2 = wown2[jj][2*q + e2];
                        acc2[jj][0] = pk_fma(w2, ha, acc2[jj][0]);
                        acc2[jj][1] = pk_fma(w2, hb, acc2[jj][1]);
                    }
                }
            }
        }

        // C. land partner half (tag-validated, retry until current)
        if (ld) {
            const float T = (float)t;
            for (;;) {
                asm volatile("s_waitcnt vmcnt(0)" ::: "memory");
                if (!__any(pv.y != T)) break;
                asm volatile("global_load_dwordx2 %0, %1, off sc0 sc1"
                             : "=&v"(pv) : "v"(pa) : "memory");
            }
            pstage[rb][pslot2] = pv.x;
        }
        __syncthreads();   // B2: pstage ready

        // D. phase2: partner-half packed FMAs, batch innermost
        {
            const float* p0 = &pstage[0][kt * 20];
            const float* p1 = &pstage[1][kt * 20];
            // k 0..7 from wpar2 regs
            #pragma unroll
            for (int q = 0; q < 2; ++q) {
                f32x4 a4 = *reinterpret_cast<const f32x4*>(p0 + q * 4);
                f32x4 b4 = *reinterpret_cast<const f32x4*>(p1 + q * 4);
                #pragma unroll
                for (int e2 = 0; e2 < 2; ++e2) {
                    f32x2 ha = f32x2{a4[2*e2], a4[2*e2+1]};
                    f32x2 hb = f32x2{b4[2*e2], b4[2*e2+1]};
                    #pragma unroll
                    for (int jj = 0; jj < 8; ++jj) {
                        f32x2 w2 = wpar2[jj][2*q + e2];
                        acc2[jj][0] = pk_fma(w2, ha, acc2[jj][0]);
                        acc2[jj][1] = pk_fma(w2, hb, acc2[jj][1]);
                    }
                }
            }
            // k 8..15 from wlds
            f32x2 hp0[4], hp1[4];
            #pragma unroll
            for (int q = 0; q < 2; ++q) {
                f32x4 a4 = *reinterpret_cast<const f32x4*>(p0 + 8 + q * 4);
                f32x4 b4 = *reinterpret_cast<const f32x4*>(p1 + 8 + q * 4);
                hp0[2*q+0] = f32x2{a4[0], a4[1]}; hp0[2*q+1] = f32x2{a4[2], a4[3]};
                hp1[2*q+0] = f32x2{b4[0], b4[1]}; hp1[2*q+1] = f32x2{b4[2], b4[3]};
            }
            #pragma unroll
            for (int jj = 0; jj < 8; ++jj) {
                #pragma unroll
                for (int h = 0; h < 2; ++h) {
                    int qq = jj * 2 + h;
                    f32x4 w4 = reinterpret_cast<const f32x4*>(wlds)[wv * 1024 + qq * 64 + ln];
                    f32x2 wA = f32x2{w4[0], w4[1]};
                    f32x2 wB = f32x2{w4[2], w4[3]};
                    acc2[jj][0] = pk_fma(wA, hp0[2*h+0], acc2[jj][0]);
                    acc2[jj][1] = pk_fma(wA, hp1[2*h+0], acc2[jj][1]);
                    acc2[jj][0] = pk_fma(wB, hp0[2*h+1], acc2[jj][0]);
                    acc2[jj][1] = pk_fma(wB, hp1[2*h+1], acc2[jj][1]);
                }
            }
        }

        // E. horizontal pair-combine, then merge-tree reduce across 16 kt-lanes:
        //    lane kt ends with value v=kt (v = b*8+jj).
        float acc[8][2];
        #pragma unroll
        for (int jj = 0; jj < 8; ++jj) {
            acc[jj][0] = acc2[jj][0][0] + acc2[jj][0][1];
            acc[jj][1] = acc2[jj][1][0] + acc2[jj][1][1];
        }
        float hsel;
        {
            const bool p1 = kt & 1, p2 = kt & 2, p3 = kt & 4, p4v = kt & 8;
            float r8[8];
            #pragma unroll
            for (int j = 0; j < 8; ++j) {                 // acc2[v]=acc[v&7][v>>3]
                float a = acc[(2*j) & 7][(2*j) >> 3];
                float b = acc[(2*j+1) & 7][(2*j+1) >> 3];
                float tt = p1 ? b : a, u = p1 ? a : b;
                r8[j] = tt + dpp_mov<0xB1>(u);            // + lane^1
            }
            float r4[4];
            #pragma unroll
            for (int j = 0; j < 4; ++j) {
                float a = r8[2*j], b = r8[2*j+1];
                float tt = p2 ? b : a, u = p2 ? a : b;
                r4[j] = tt + dpp_mov<0x4E>(u);            // + lane^2
            }
            float r2[2];
            #pragma unroll
            for (int j = 0; j < 2; ++j) {
                float a = r4[2*j], b = r4[2*j+1];
                float tt = p3 ? b : a, u = p3 ? a : b;
                r2[j] = tt + swz_xor4(u);                 // + lane^4
            }
            float a = r2[0], b = r2[1];
            float tt = p4v ? b : a, u = p4v ? a : b;
            hsel = tt + dpp_mov<0x128>(u);                // row_ror:8 = + lane^8
        }

        // F. epilogue: x-projection, ReLU, store everywhere
        float xv0 = xs[bw][t * 2 + 0], xv1 = xs[bw][t * 2 + 1];
        float hnew = fmaxf(__builtin_fmaf(xv0, wx0, __builtin_fmaf(xv1, wx1, hsel)), 0.f);

        hbuf[cur ^ 1][bw][wslot] = hnew;                          // next step's phase1
        out[(size_t)(t + 1) * ostep + (size_t)(b0 + bw) * HH + jw] = hnew;  // output
        {
            f32x2 pb2; pb2.x = hnew; pb2.y = (float)(t + 1);      // tagged publish
            f32x2* pd = pub + (((t + 1) & 1) ? XELEMS : 0);
            asm volatile("global_store_dwordx2 %0, %1, off sc0 sc1"
                         :: "v"(pd), "v"(pb2) : "memory");
        }
        __syncthreads();   // B3: hbuf[cur^1] complete
        cur ^= 1;
    }
}

extern "C" void kernel_launch(void* const* d_in, const int* in_sizes, int n_in,
                              void* d_out, int out_size, void* d_ws, size_t ws_size,
                              hipStream_t stream) {
    const float* x  = (const float*)d_in[0];
    const float* Wh = (const float*)d_in[1];
    const float* Wx = (const float*)d_in[2];
    float* out = (float*)d_out;
    f32x2* xch = (f32x2*)d_ws;    // needs 2*256*512*8 = 2 MB of workspace
    rnn_pair_kernel<<<BB, NTH, 0, stream>>>(x, Wh, Wx, out, xch);
}

// Round 8
// 1448.130 us; speedup vs baseline: 1.1732x; 1.1732x over previous
//
#include <hip/hip_runtime.h>

#define BB 256
#define TT 512
#define HH 512
#define NTH 512
#define XELEMS (BB * HH)   // f32x2 elements per exchange ping-pong slot

typedef float f32x4 __attribute__((ext_vector_type(4)));
typedef float f32x2 __attribute__((ext_vector_type(2)));

// packed fp32 FMA -> v_pk_fma_f32
__device__ __forceinline__ f32x2 pk_fma(f32x2 a, f32x2 b, f32x2 c) {
    return __builtin_elementwise_fma(a, b, c);
}
// cross-lane move via DPP (VALU pipe)
template<int CTRL>
__device__ __forceinline__ float dpp_mov(float v) {
    return __builtin_bit_cast(float, __builtin_amdgcn_update_dpp(
        0, __builtin_bit_cast(int, v), CTRL, 0xf, 0xf, true));
}
// lane ^= 4 via ds_swizzle (xor_mask=4, and_mask=0x1F)
__device__ __forceinline__ float swz_xor4(float v) {
    return __builtin_bit_cast(float, __builtin_amdgcn_ds_swizzle(
        __builtin_bit_cast(int, v), 0x101F));
}
// padded h index: +4 floats per 32-float chunk -> conflict-spread b128 reads
__device__ __forceinline__ int padofs(int k) { return k + ((k >> 5) << 2); }

// Quad-split RNN: 64 groups x 4 WGs; group g owns batches 4g..4g+3; member q
// owns j-rows [128q,128q+128) x all 512 k. Weights: 64 fl/thread in arch VGPRs
// (quarters q,q+1) + 64 fl/thread in LDS (quarters q+2,q+3) -> fits the
// observed 128-arch-VGPR cap with no AGPR round-trips (R7's regression).
// Exchange: tagged (h, t) f32x2 ping-pong in d_ws, sc0sc1 (L3-coherent);
// depth-2 + group lockstep makes overwrite-before-consume impossible; stale
// tags from prior replays carry identical deterministic values.
// LDS 146.5 KB also guarantees 1 WG/CU -> all 256 WGs co-resident.
__global__ void
__attribute__((amdgpu_flat_work_group_size(NTH, NTH)))
__attribute__((amdgpu_waves_per_eu(2, 2)))
rnn_quad_kernel(
    const float* __restrict__ x,    // [B, T, 2]
    const float* __restrict__ Wh,   // [H, H]
    const float* __restrict__ Wx,   // [H, 2]
    float* __restrict__ out,        // [T+1, B, H]
    f32x2* __restrict__ xch)        // [2][B][H] (value, tag)
{
    const int bid = blockIdx.x;
    const int tid = threadIdx.x;
    const int q   = bid & 3;               // owned j-quarter
    const int g   = bid >> 2;
    const int b0  = g * 4;                 // 4 batches per group
    const int kt  = tid & 15;              // k-chunk: 8 k per quarter
    const int jg  = tid >> 4;              // j-group 0..31 (4 rows each)

    __shared__ f32x4 wlds4[16][NTH];                 // 128 KB: weight quarters q+2,q+3
    __shared__ __align__(16) float hs[2][4][580];    // 18.6 KB: double-buffered h (padded)

    // ---- weights: quarters qi=0,1 -> 32 f32x2 regs; qi=2,3 -> LDS (lane-major) ----
    f32x2 w2[4][2][4];
    #pragma unroll
    for (int j4 = 0; j4 < 4; ++j4) {
        const float* row = Wh + (size_t)(128 * q + jg * 4 + j4) * HH + kt * 8;
        #pragma unroll
        for (int qi = 0; qi < 2; ++qi) {
            const f32x4* p4 = reinterpret_cast<const f32x4*>(row + 128 * ((q + qi) & 3));
            f32x4 v0 = p4[0], v1 = p4[1];
            w2[j4][qi][0] = f32x2{v0[0], v0[1]};
            w2[j4][qi][1] = f32x2{v0[2], v0[3]};
            w2[j4][qi][2] = f32x2{v1[0], v1[1]};
            w2[j4][qi][3] = f32x2{v1[2], v1[3]};
        }
        #pragma unroll
        for (int qi = 2; qi < 4; ++qi) {
            const f32x4* p4 = reinterpret_cast<const f32x4*>(row + 128 * ((q + qi) & 3));
            wlds4[(qi - 2) * 8 + j4 * 2 + 0][tid] = p4[0];
            wlds4[(qi - 2) * 8 + j4 * 2 + 1][tid] = p4[1];
        }
    }

    // ---- hs[0] zero, h0[0]=1; out[0] ----
    for (int i = tid; i < 4 * 580; i += NTH) (&hs[0][0][0])[i] = 0.f;
    {
        int b = tid >> 7, jl = tid & 127;
        out[(size_t)(b0 + b) * HH + 128 * q + jl] = (128 * q + jl == 0) ? 1.f : 0.f;
    }
    __syncthreads();
    if (tid < 4) hs[0][tid][0] = 1.f;

    // writer identity: lane kt keeps value v=kt -> (batch kt>>2, col jg*4+(kt&3))
    const int bw = kt >> 2;
    const int jw = 128 * q + jg * 4 + (kt & 3);
    const float wx0 = Wx[jw * 2 + 0];
    const float wx1 = Wx[jw * 2 + 1];
    const float* xrow = x + (size_t)(b0 + bw) * (TT * 2);
    const size_t ostep = (size_t)BB * HH;

    // exchange addressing: read (b=tid>>7, j=tid&127) of each partner quarter
    const int rb = tid >> 7, rj = tid & 127;
    const int Q1 = (q + 1) & 3, Q2 = (q + 2) & 3, Q3 = (q + 3) & 3;
    const f32x2* rbase = xch + (size_t)(b0 + rb) * HH;
    const f32x2* r1 = rbase + 128 * Q1 + rj;
    const f32x2* r2 = rbase + 128 * Q2 + rj;
    const f32x2* r3 = rbase + 128 * Q3 + rj;
    f32x2* pubp = xch + (size_t)(b0 + bw) * HH + jw;
    const int land1 = padofs(128 * Q1 + rj);
    const int land2 = padofs(128 * Q2 + rj);
    const int land3 = padofs(128 * Q3 + rj);

    __syncthreads();
    int cur = 0;

    for (int t = 0; t < TT; ++t) {
        // A. issue tagged partner loads (t=0: hs[0] fully prefilled) + x pair
        f32x2 pv1, pv2, pv3;
        const bool ld = (t > 0);
        const size_t so = (size_t)(t & 1) * XELEMS;
        if (ld) {
            asm volatile("global_load_dwordx2 %0, %3, off sc0 sc1\n\t"
                         "global_load_dwordx2 %1, %4, off sc0 sc1\n\t"
                         "global_load_dwordx2 %2, %5, off sc0 sc1"
                         : "=&v"(pv1), "=&v"(pv2), "=&v"(pv3)
                         : "v"(r1 + so), "v"(r2 + so), "v"(r3 + so) : "memory");
        }
        f32x2 xv = *reinterpret_cast<const f32x2*>(xrow + 2 * t);

        // B. own quarter (qi=0) from register weights, h from LDS
        f32x2 acc2[4][4];   // [j4][b]
        #pragma unroll
        for (int j4 = 0; j4 < 4; ++j4)
            #pragma unroll
            for (int b = 0; b < 4; ++b) acc2[j4][b] = f32x2{0.f, 0.f};
        {
            const int ko = padofs(128 * q + kt * 8);
            #pragma unroll
            for (int b = 0; b < 4; ++b) {
                const float* hp = &hs[cur][b][ko];
                f32x4 u0 = *reinterpret_cast<const f32x4*>(hp);
                f32x4 u1 = *reinterpret_cast<const f32x4*>(hp + 4);
                f32x2 h2[4] = {{u0[0],u0[1]},{u0[2],u0[3]},{u1[0],u1[1]},{u1[2],u1[3]}};
                #pragma unroll
                for (int p = 0; p < 4; ++p)
                    #pragma unroll
                    for (int j4 = 0; j4 < 4; ++j4)
                        acc2[j4][b] = pk_fma(w2[j4][0][p], h2[p], acc2[j4][b]);
            }
        }

        // C. tag-validate + land partner quarters into hs[cur]
        if (ld) {
            const float T = (float)t;
            for (;;) {
                asm volatile("s_waitcnt vmcnt(0)" ::: "memory");
                bool bad = (pv1.y != T) | (pv2.y != T) | (pv3.y != T);
                if (!__any(bad)) break;
                asm volatile("global_load_dwordx2 %0, %3, off sc0 sc1\n\t"
                             "global_load_dwordx2 %1, %4, off sc0 sc1\n\t"
                             "global_load_dwordx2 %2, %5, off sc0 sc1"
                             : "=&v"(pv1), "=&v"(pv2), "=&v"(pv3)
                             : "v"(r1 + so), "v"(r2 + so), "v"(r3 + so) : "memory");
            }
            hs[cur][rb][land1] = pv1.x;
            hs[cur][rb][land2] = pv2.x;
            hs[cur][rb][land3] = pv3.x;
        }
        __syncthreads();   // B2: hs[cur] complete

        // D. partner quarters: qi=1 from regs, qi=2,3 weights from LDS
        {
            const int ko = padofs(128 * Q1 + kt * 8);
            #pragma unroll
            for (int b = 0; b < 4; ++b) {
                const float* hp = &hs[cur][b][ko];
                f32x4 u0 = *reinterpret_cast<const f32x4*>(hp);
                f32x4 u1 = *reinterpret_cast<const f32x4*>(hp + 4);
                f32x2 h2[4] = {{u0[0],u0[1]},{u0[2],u0[3]},{u1[0],u1[1]},{u1[2],u1[3]}};
                #pragma unroll
                for (int p = 0; p < 4; ++p)
                    #pragma unroll
                    for (int j4 = 0; j4 < 4; ++j4)
                        acc2[j4][b] = pk_fma(w2[j4][1][p], h2[p], acc2[j4][b]);
            }
        }
        #pragma unroll
        for (int qi = 2; qi < 4; ++qi) {
            const int ko = padofs(128 * ((qi == 2) ? Q2 : Q3) + kt * 8);
            #pragma unroll
            for (int b = 0; b < 4; ++b) {
                const float* hp = &hs[cur][b][ko];
                f32x4 u0 = *reinterpret_cast<const f32x4*>(hp);
                f32x4 u1 = *reinterpret_cast<const f32x4*>(hp + 4);
                f32x2 h2[4] = {{u0[0],u0[1]},{u0[2],u0[3]},{u1[0],u1[1]},{u1[2],u1[3]}};
                #pragma unroll
                for (int j4 = 0; j4 < 4; ++j4) {
                    f32x4 wa = wlds4[(qi - 2) * 8 + j4 * 2 + 0][tid];
                    f32x4 wb = wlds4[(qi - 2) * 8 + j4 * 2 + 1][tid];
                    acc2[j4][b] = pk_fma(f32x2{wa[0], wa[1]}, h2[0], acc2[j4][b]);
                    acc2[j4][b] = pk_fma(f32x2{wa[2], wa[3]}, h2[1], acc2[j4][b]);
                    acc2[j4][b] = pk_fma(f32x2{wb[0], wb[1]}, h2[2], acc2[j4][b]);
                    acc2[j4][b] = pk_fma(f32x2{wb[2], wb[3]}, h2[3], acc2[j4][b]);
                }
            }
        }

        // E. horizontal add, then 16-lane merge tree (lane kt ends with v=kt)
        float val[16];
        #pragma unroll
        for (int v = 0; v < 16; ++v)
            val[v] = acc2[v & 3][v >> 2][0] + acc2[v & 3][v >> 2][1];
        float hsel;
        {
            const bool p1 = kt & 1, p2 = kt & 2, p3 = kt & 4, p4v = kt & 8;
            float r8[8];
            #pragma unroll
            for (int j = 0; j < 8; ++j) {
                float a = val[2*j], b = val[2*j+1];
                float tt = p1 ? b : a, u = p1 ? a : b;
                r8[j] = tt + dpp_mov<0xB1>(u);            // + lane^1
            }
            float r4[4];
            #pragma unroll
            for (int j = 0; j < 4; ++j) {
                float a = r8[2*j], b = r8[2*j+1];
                float tt = p2 ? b : a, u = p2 ? a : b;
                r4[j] = tt + dpp_mov<0x4E>(u);            // + lane^2
            }
            float r2f[2];
            #pragma unroll
            for (int j = 0; j < 2; ++j) {
                float a = r4[2*j], b = r4[2*j+1];
                float tt = p3 ? b : a, u = p3 ? a : b;
                r2f[j] = tt + swz_xor4(u);                // + lane^4
            }
            float a = r2f[0], b = r2f[1];
            float tt = p4v ? b : a, u = p4v ? a : b;
            hsel = tt + dpp_mov<0x128>(u);                // row_ror:8 = + lane^8
        }

        // F. epilogue: x-projection, ReLU; publish first (latency-critical)
        float hnew = fmaxf(__builtin_fmaf(xv[0], wx0,
                           __builtin_fmaf(xv[1], wx1, hsel)), 0.f);
        {
            f32x2 pb2; pb2.x = hnew; pb2.y = (float)(t + 1);
            f32x2* pd = pubp + (size_t)((t + 1) & 1) * XELEMS;
            asm volatile("global_store_dwordx2 %0, %1, off sc0 sc1"
                         :: "v"(pd), "v"(pb2) : "memory");
        }
        hs[cur ^ 1][bw][padofs(jw)] = hnew;
        out[(size_t)(t + 1) * ostep + (size_t)(b0 + bw) * HH + jw] = hnew;
        __syncthreads();   // B3: hs[cur^1] own quarter complete
        cur ^= 1;
    }
}

extern "C" void kernel_launch(void* const* d_in, const int* in_sizes, int n_in,
                              void* d_out, int out_size, void* d_ws, size_t ws_size,
                              hipStream_t stream) {
    const float* x  = (const float*)d_in[0];
    const float* Wh = (const float*)d_in[1];
    const float* Wx = (const float*)d_in[2];
    float* out = (float*)d_out;
    f32x2* xch = (f32x2*)d_ws;    // 2*256*512*8 = 2 MB of workspace
    rnn_quad_kernel<<<BB, NTH, 0, stream>>>(x, Wh, Wx, out, xch);
}